// Round 4
// baseline (363.102 us; speedup 1.0000x reference)
//
#include <hip/hip_runtime.h>
#include <hip/hip_bf16.h>

// StandAloneSelfAttention: B=4, H=W=64, C=128, heads=8, hsize=16, K=7x7=49.
// Two-kernel plan:
//   1) proj: q/k/v = x @ W + b   (three 16384x128 @ 128x128 f32 GEMMs) -> d_ws
//   2) attn: per-pixel 7x7-window attention with online softmax.

constexpr int BB = 4;
constexpr int HH = 64;
constexpr int WW = 64;
constexpr int C  = 128;
constexpr int F  = 128;
constexpr int NPIX = BB * HH * WW;   // 16384

// ---------------------------------------------------------------- proj ------
__device__ __forceinline__ void do_proj(const float* __restrict__ W,
                                        const float* __restrict__ bias,
                                        float* __restrict__ outp,
                                        const float* __restrict__ xs,
                                        int p0, int tp, int tc)
{
    float acc[4][8];
#pragma unroll
    for (int i = 0; i < 4; ++i)
#pragma unroll
        for (int j = 0; j < 8; ++j) acc[i][j] = 0.f;

#pragma unroll 4
    for (int c = 0; c < 128; ++c) {
        const float4 w0 = *(const float4*)(W + c * 128 + tc * 8);
        const float4 w1 = *(const float4*)(W + c * 128 + tc * 8 + 4);
        const float wv[8] = {w0.x, w0.y, w0.z, w0.w, w1.x, w1.y, w1.z, w1.w};
        float xv[4];
#pragma unroll
        for (int i = 0; i < 4; ++i) xv[i] = xs[c * 65 + tp * 4 + i];
#pragma unroll
        for (int i = 0; i < 4; ++i)
#pragma unroll
            for (int j = 0; j < 8; ++j) acc[i][j] = fmaf(xv[i], wv[j], acc[i][j]);
    }

    float bv[8];
#pragma unroll
    for (int j = 0; j < 8; ++j) bv[j] = bias[tc * 8 + j];

#pragma unroll
    for (int i = 0; i < 4; ++i) {
        float4 o0, o1;
        o0.x = acc[i][0] + bv[0];
        o0.y = acc[i][1] + bv[1];
        o0.z = acc[i][2] + bv[2];
        o0.w = acc[i][3] + bv[3];
        o1.x = acc[i][4] + bv[4];
        o1.y = acc[i][5] + bv[5];
        o1.z = acc[i][6] + bv[6];
        o1.w = acc[i][7] + bv[7];
        float* dst = outp + (size_t)(p0 + tp * 4 + i) * F + tc * 8;
        *(float4*)(dst)     = o0;
        *(float4*)(dst + 4) = o1;
    }
}

__global__ __launch_bounds__(256) void proj_kernel(
    const float* __restrict__ x,
    const float* __restrict__ Wq, const float* __restrict__ bq,
    const float* __restrict__ Wk, const float* __restrict__ bk,
    const float* __restrict__ Wv, const float* __restrict__ bv,
    float* __restrict__ qo, float* __restrict__ ko, float* __restrict__ vo)
{
    __shared__ float xs[128 * 65];   // xs[c][p], stride 65 (bank-conflict-free)
    const int t  = threadIdx.x;
    const int p0 = blockIdx.x * 64;

    // load x[p0 .. p0+63][0..127] transposed into LDS (coalesced global reads)
    for (int idx = t; idx < 64 * 128; idx += 256) {
        const int p = idx >> 7;
        const int c = idx & 127;
        xs[c * 65 + p] = x[(size_t)p0 * C + idx];
    }
    __syncthreads();

    const int tp = t >> 4;   // 0..15 : pixel group (4 pixels each)
    const int tc = t & 15;   // 0..15 : channel group (8 channels each)

    do_proj(Wq, bq, qo, xs, p0, tp, tc);
    do_proj(Wk, bk, ko, xs, p0, tp, tc);
    do_proj(Wv, bv, vo, xs, p0, tp, tc);
}

// ---------------------------------------------------------------- attn ------
__global__ __launch_bounds__(128) void attn_kernel(
    const float* __restrict__ q, const float* __restrict__ k,
    const float* __restrict__ v, const float* __restrict__ emb0,
    const float* __restrict__ emb1, float* __restrict__ out)
{
    const int pix = blockIdx.x;
    const int t   = threadIdx.x;          // channel f = h*16 + d
    const int b   = pix >> 12;
    const int xr  = (pix >> 6) & 63;
    const int yc  = pix & 63;

    const float qv = q[(size_t)pix * F + t];

    // emb[f][i][j] = f<64 ? emb0[f*7+i] : emb1[(f-64)*7+j]
    float ev[7];
    if (t < 64) {
#pragma unroll
        for (int i = 0; i < 7; ++i) ev[i] = emb0[t * 7 + i];
    } else {
#pragma unroll
        for (int i = 0; i < 7; ++i) ev[i] = emb1[(t - 64) * 7 + i];
    }

    float m = -1e30f, l = 0.f, o = 0.f;

#pragma unroll
    for (int kk = 0; kk < 49; ++kk) {
        const int i  = kk / 7;
        const int j  = kk % 7;
        const int xi = xr + i - 3;
        const int yj = yc + j - 3;
        const bool inb = ((unsigned)xi < 64u) && ((unsigned)yj < 64u); // block-uniform

        float kval = 0.f, vval = 0.f;
        if (inb) {
            const int np = (((b << 6) | xi) << 6) | yj;
            kval = k[(size_t)np * F + t];
            vval = v[(size_t)np * F + t];
        }
        kval += (t < 64) ? ev[i] : ev[j];   // OOB: key = emb (matches reference)

        float s = qv * kval;
        s += __shfl_xor(s, 1);
        s += __shfl_xor(s, 2);
        s += __shfl_xor(s, 4);
        s += __shfl_xor(s, 8);   // all 16 lanes of the head now hold the score

        const float mn  = fmaxf(m, s);
        const float cor = __expf(m - mn);
        const float pe  = __expf(s - mn);
        l = l * cor + pe;
        o = o * cor + pe * vval;
        m = mn;
    }

    out[(size_t)pix * F + t] = o / l;
}

// --------------------------------------------------------------- launch -----
extern "C" void kernel_launch(void* const* d_in, const int* in_sizes, int n_in,
                              void* d_out, int out_size, void* d_ws, size_t ws_size,
                              hipStream_t stream)
{
    const float* x    = (const float*)d_in[0];
    const float* Wq   = (const float*)d_in[1];
    const float* bq   = (const float*)d_in[2];
    const float* Wk   = (const float*)d_in[3];
    const float* bk   = (const float*)d_in[4];
    const float* Wv   = (const float*)d_in[5];
    const float* bv   = (const float*)d_in[6];
    const float* emb0 = (const float*)d_in[7];
    const float* emb1 = (const float*)d_in[8];
    float* out = (float*)d_out;

    float* qb = (float*)d_ws;
    float* kb = qb + (size_t)NPIX * F;
    float* vb = kb + (size_t)NPIX * F;

    proj_kernel<<<NPIX / 64, 256, 0, stream>>>(x, Wq, bq, Wk, bk, Wv, bv, qb, kb, vb);
    attn_kernel<<<NPIX, 128, 0, stream>>>(qb, kb, vb, emb0, emb1, out);
}

// Round 5
// 164.208 us; speedup vs baseline: 2.2112x; 2.2112x over previous
//
#include <hip/hip_runtime.h>
#include <hip/hip_bf16.h>

// StandAloneSelfAttention: B=4, H=W=64, C=128, heads=8, hsize=16, K=7x7=49.
//   1) proj: q/k/v = x @ W + b  (one GEMM per block; 768 blocks -> 3 waves/SIMD)
//   2) attn: thread = (pixel, head); no shuffles; emb folded into qe[7].

constexpr int BB = 4;
constexpr int HH = 64;
constexpr int WW = 64;
constexpr int C  = 128;
constexpr int F  = 128;
constexpr int NPIX = BB * HH * WW;   // 16384

// ---------------------------------------------------------------- proj ------
__device__ __forceinline__ void do_proj(const float* __restrict__ W,
                                        const float* __restrict__ bias,
                                        float* __restrict__ outp,
                                        const float* __restrict__ xs,
                                        int p0, int tp, int tc)
{
    float acc[4][8];
#pragma unroll
    for (int i = 0; i < 4; ++i)
#pragma unroll
        for (int j = 0; j < 8; ++j) acc[i][j] = 0.f;

#pragma unroll 4
    for (int c = 0; c < 128; ++c) {
        const float4 w0 = *(const float4*)(W + c * 128 + tc * 8);
        const float4 w1 = *(const float4*)(W + c * 128 + tc * 8 + 4);
        const float wv[8] = {w0.x, w0.y, w0.z, w0.w, w1.x, w1.y, w1.z, w1.w};
        float xv[4];
#pragma unroll
        for (int i = 0; i < 4; ++i) xv[i] = xs[c * 65 + tp * 4 + i];
#pragma unroll
        for (int i = 0; i < 4; ++i)
#pragma unroll
            for (int j = 0; j < 8; ++j) acc[i][j] = fmaf(xv[i], wv[j], acc[i][j]);
    }

    float bv[8];
#pragma unroll
    for (int j = 0; j < 8; ++j) bv[j] = bias[tc * 8 + j];

#pragma unroll
    for (int i = 0; i < 4; ++i) {
        float4 o0, o1;
        o0.x = acc[i][0] + bv[0];
        o0.y = acc[i][1] + bv[1];
        o0.z = acc[i][2] + bv[2];
        o0.w = acc[i][3] + bv[3];
        o1.x = acc[i][4] + bv[4];
        o1.y = acc[i][5] + bv[5];
        o1.z = acc[i][6] + bv[6];
        o1.w = acc[i][7] + bv[7];
        float* dst = outp + (size_t)(p0 + tp * 4 + i) * F + tc * 8;
        *(float4*)(dst)     = o0;
        *(float4*)(dst + 4) = o1;
    }
}

__global__ __launch_bounds__(256) void proj_kernel(
    const float* __restrict__ x,
    const float* __restrict__ Wq, const float* __restrict__ bq,
    const float* __restrict__ Wk, const float* __restrict__ bk,
    const float* __restrict__ Wv, const float* __restrict__ bv,
    float* __restrict__ qo, float* __restrict__ ko, float* __restrict__ vo)
{
    __shared__ float xs[128 * 65];   // xs[c][p], stride 65 (bank-conflict-free)
    const int t    = threadIdx.x;
    const int g    = blockIdx.x % 3;     // which GEMM (q/k/v) — adjacent blocks
    const int tile = blockIdx.x / 3;     // share the x tile via L2
    const int p0   = tile * 64;

    for (int idx = t; idx < 64 * 128; idx += 256) {
        const int p = idx >> 7;
        const int c = idx & 127;
        xs[c * 65 + p] = x[(size_t)p0 * C + idx];
    }
    __syncthreads();

    const float* W; const float* bias; float* outp;
    if (g == 0)      { W = Wq; bias = bq; outp = qo; }
    else if (g == 1) { W = Wk; bias = bk; outp = ko; }
    else             { W = Wv; bias = bv; outp = vo; }

    do_proj(W, bias, outp, xs, p0, t >> 4, t & 15);
}

// ---------------------------------------------------------------- attn ------
// thread = (pixel, head): block = 32 pixels x 8 heads = 256 threads.
__global__ __launch_bounds__(256, 2) void attn_kernel(
    const float* __restrict__ q, const float* __restrict__ k,
    const float* __restrict__ v, const float* __restrict__ emb0,
    const float* __restrict__ emb1, float* __restrict__ out)
{
    const int t   = threadIdx.x;
    const int pl  = t >> 3;               // 0..31
    const int h   = t & 7;                // head
    const int pix = blockIdx.x * 32 + pl;
    const int xr  = (pix >> 6) & 63;
    const int yc  = pix & 63;

    // q fragment (16 floats) in registers
    const float* qp = q + (size_t)pix * F + h * 16;
    float qv[16];
    *(float4*)(&qv[0])  = ((const float4*)qp)[0];
    *(float4*)(&qv[4])  = ((const float4*)qp)[1];
    *(float4*)(&qv[8])  = ((const float4*)qp)[2];
    *(float4*)(&qv[12]) = ((const float4*)qp)[3];

    // qe[a] = sum_d q[d] * emb[f=h*16+d][a]; emb0 depends only on i, emb1 only on j
    const float* E = (h < 4) ? (emb0 + h * 16 * 7) : (emb1 + (h - 4) * 16 * 7);
    float qe[7] = {0.f, 0.f, 0.f, 0.f, 0.f, 0.f, 0.f};
#pragma unroll
    for (int d = 0; d < 16; ++d) {
#pragma unroll
        for (int a = 0; a < 7; ++a)
            qe[a] = fmaf(qv[d], E[d * 7 + a], qe[a]);
    }

    float m = -1e30f, l = 0.f;
    float o[16];
#pragma unroll
    for (int d = 0; d < 16; ++d) o[d] = 0.f;

#pragma unroll
    for (int i = 0; i < 7; ++i) {
        const int  xi    = xr + i - 3;
        const bool rowin = ((unsigned)xi < 64u);
        const int  npb   = pix + (i - 3) * 64 - 3;

        // --- 7 independent scores for this key row ---
        float s[7];
#pragma unroll
        for (int j = 0; j < 7; ++j) {
            const int  yj  = yc + j - 3;
            const bool inb = rowin && ((unsigned)yj < 64u);
            int np = npb + j;
            np = min(max(np, 0), NPIX - 1);          // clamp; OOB value discarded
            const float* kp = k + (size_t)np * F + h * 16;
            float kb[16];
            *(float4*)(&kb[0])  = ((const float4*)kp)[0];
            *(float4*)(&kb[4])  = ((const float4*)kp)[1];
            *(float4*)(&kb[8])  = ((const float4*)kp)[2];
            *(float4*)(&kb[12]) = ((const float4*)kp)[3];
            float d0 = 0.f, d1 = 0.f, d2 = 0.f, d3 = 0.f;
#pragma unroll
            for (int d = 0; d < 4; ++d) {
                d0 = fmaf(qv[d],      kb[d],      d0);
                d1 = fmaf(qv[4 + d],  kb[4 + d],  d1);
                d2 = fmaf(qv[8 + d],  kb[8 + d],  d2);
                d3 = fmaf(qv[12 + d], kb[12 + d], d3);
            }
            const float dot = (d0 + d1) + (d2 + d3);
            // OOB key: k contribution = 0, emb term remains (matches reference)
            s[j] = (inb ? dot : 0.f) + ((h < 4) ? qe[i] : qe[j]);
        }

        // --- online softmax update for the row (independent exps -> ILP) ---
        const float rm = fmaxf(fmaxf(fmaxf(s[0], s[1]), fmaxf(s[2], s[3])),
                               fmaxf(fmaxf(s[4], s[5]), s[6]));
        const float mn  = fmaxf(m, rm);
        const float cor = __expf(m - mn);
        float p[7];
#pragma unroll
        for (int j = 0; j < 7; ++j) p[j] = __expf(s[j] - mn);
        l = l * cor + (((p[0] + p[1]) + (p[2] + p[3])) + ((p[4] + p[5]) + p[6]));
        m = mn;
#pragma unroll
        for (int d = 0; d < 16; ++d) o[d] *= cor;

        // --- PV accumulate ---
#pragma unroll
        for (int j = 0; j < 7; ++j) {
            const int  yj  = yc + j - 3;
            const bool inb = rowin && ((unsigned)yj < 64u);
            int np = npb + j;
            np = min(max(np, 0), NPIX - 1);
            const float* vp = v + (size_t)np * F + h * 16;
            float vb[16];
            *(float4*)(&vb[0])  = ((const float4*)vp)[0];
            *(float4*)(&vb[4])  = ((const float4*)vp)[1];
            *(float4*)(&vb[8])  = ((const float4*)vp)[2];
            *(float4*)(&vb[12]) = ((const float4*)vp)[3];
            const float pj = inb ? p[j] : 0.f;       // OOB v contributes 0
#pragma unroll
            for (int d = 0; d < 16; ++d) o[d] = fmaf(pj, vb[d], o[d]);
        }
    }

    const float inv = 1.f / l;
    float* op = out + (size_t)pix * F + h * 16;
    float ov[16];
#pragma unroll
    for (int d = 0; d < 16; ++d) ov[d] = o[d] * inv;
    ((float4*)op)[0] = *(float4*)(&ov[0]);
    ((float4*)op)[1] = *(float4*)(&ov[4]);
    ((float4*)op)[2] = *(float4*)(&ov[8]);
    ((float4*)op)[3] = *(float4*)(&ov[12]);
}

// --------------------------------------------------------------- launch -----
extern "C" void kernel_launch(void* const* d_in, const int* in_sizes, int n_in,
                              void* d_out, int out_size, void* d_ws, size_t ws_size,
                              hipStream_t stream)
{
    const float* x    = (const float*)d_in[0];
    const float* Wq   = (const float*)d_in[1];
    const float* bq   = (const float*)d_in[2];
    const float* Wk   = (const float*)d_in[3];
    const float* bk   = (const float*)d_in[4];
    const float* Wv   = (const float*)d_in[5];
    const float* bv   = (const float*)d_in[6];
    const float* emb0 = (const float*)d_in[7];
    const float* emb1 = (const float*)d_in[8];
    float* out = (float*)d_out;

    float* qb = (float*)d_ws;
    float* kb = qb + (size_t)NPIX * F;
    float* vb = kb + (size_t)NPIX * F;

    proj_kernel<<<(NPIX / 64) * 3, 256, 0, stream>>>(x, Wq, bq, Wk, bk, Wv, bv, qb, kb, vb);
    attn_kernel<<<NPIX / 32, 256, 0, stream>>>(qb, kb, vb, emb0, emb1, out);
}

// Round 11
// 159.437 us; speedup vs baseline: 2.2774x; 1.0299x over previous
//
#include <hip/hip_runtime.h>
#include <hip/hip_bf16.h>

// StandAloneSelfAttention: B=4, H=W=64, C=128, heads=8, hsize=16, K=7x7=49.
//   1) proj: q/k/v = x @ W + b  (one GEMM per block; 768 blocks, XCD-swizzled)
//   2) attn: thread = (pixel, head); batched K/V register loads (28 in flight),
//      XCD-swizzled blocks for L2 locality; VGPR budget is free (grid-limited
//      occupancy: 2048 waves / 256 CU = 8 waves/CU even at 256 VGPR).

constexpr int BB = 4;
constexpr int HH = 64;
constexpr int WW = 64;
constexpr int C  = 128;
constexpr int F  = 128;
constexpr int NPIX = BB * HH * WW;   // 16384

// ---------------------------------------------------------------- proj ------
__device__ __forceinline__ void do_proj(const float* __restrict__ W,
                                        const float* __restrict__ bias,
                                        float* __restrict__ outp,
                                        const float* __restrict__ xs,
                                        int p0, int tp, int tc)
{
    float acc[4][8];
#pragma unroll
    for (int i = 0; i < 4; ++i)
#pragma unroll
        for (int j = 0; j < 8; ++j) acc[i][j] = 0.f;

#pragma unroll 8
    for (int c = 0; c < 128; ++c) {
        const float4 w0 = *(const float4*)(W + c * 128 + tc * 8);
        const float4 w1 = *(const float4*)(W + c * 128 + tc * 8 + 4);
        const float wv[8] = {w0.x, w0.y, w0.z, w0.w, w1.x, w1.y, w1.z, w1.w};
        float xv[4];
#pragma unroll
        for (int i = 0; i < 4; ++i) xv[i] = xs[c * 65 + tp * 4 + i];
#pragma unroll
        for (int i = 0; i < 4; ++i)
#pragma unroll
            for (int j = 0; j < 8; ++j) acc[i][j] = fmaf(xv[i], wv[j], acc[i][j]);
    }

    float bv[8];
#pragma unroll
    for (int j = 0; j < 8; ++j) bv[j] = bias[tc * 8 + j];

#pragma unroll
    for (int i = 0; i < 4; ++i) {
        float4 o0, o1;
        o0.x = acc[i][0] + bv[0];
        o0.y = acc[i][1] + bv[1];
        o0.z = acc[i][2] + bv[2];
        o0.w = acc[i][3] + bv[3];
        o1.x = acc[i][4] + bv[4];
        o1.y = acc[i][5] + bv[5];
        o1.z = acc[i][6] + bv[6];
        o1.w = acc[i][7] + bv[7];
        float* dst = outp + (size_t)(p0 + tp * 4 + i) * F + tc * 8;
        *(float4*)(dst)     = o0;
        *(float4*)(dst + 4) = o1;
    }
}

__global__ __launch_bounds__(256, 3) void proj_kernel(
    const float* __restrict__ x,
    const float* __restrict__ Wq, const float* __restrict__ bq,
    const float* __restrict__ Wk, const float* __restrict__ bk,
    const float* __restrict__ Wv, const float* __restrict__ bv,
    float* __restrict__ qo, float* __restrict__ ko, float* __restrict__ vo)
{
    __shared__ float xs[128 * 65];   // xs[c][p], stride 65 (bank-conflict-free)
    const int t   = threadIdx.x;
    // XCD swizzle: 768 blocks, 96 per XCD (768 % 8 == 0 -> bijective).
    const int bid = blockIdx.x;
    const int swz = (bid & 7) * 96 + (bid >> 3);
    const int g    = swz % 3;            // which GEMM (q/k/v)
    const int tile = swz / 3;            // 32 consecutive tiles per XCD
    const int p0   = tile * 64;

    for (int idx = t; idx < 64 * 128; idx += 256) {
        const int p = idx >> 7;
        const int c = idx & 127;
        xs[c * 65 + p] = x[(size_t)p0 * C + idx];
    }
    __syncthreads();

    const float* W; const float* bias; float* outp;
    if (g == 0)      { W = Wq; bias = bq; outp = qo; }
    else if (g == 1) { W = Wk; bias = bk; outp = ko; }
    else             { W = Wv; bias = bv; outp = vo; }

    do_proj(W, bias, outp, xs, p0, t >> 4, t & 15);
}

// ---------------------------------------------------------------- attn ------
// thread = (pixel, head): block = 32 pixels x 8 heads = 256 threads.
__global__ __launch_bounds__(256, 1) void attn_kernel(
    const float* __restrict__ q, const float* __restrict__ k,
    const float* __restrict__ v, const float* __restrict__ emb0,
    const float* __restrict__ emb1, float* __restrict__ out)
{
    // XCD swizzle: 512 blocks, 64 per XCD -> each XCD owns 32 contiguous
    // image rows; K/V working set ~3.4 MB fits its 4 MB L2.
    const int bid = blockIdx.x;
    const int swz = (bid & 7) * 64 + (bid >> 3);

    const int t   = threadIdx.x;
    const int pl  = t >> 3;               // 0..31
    const int h   = t & 7;                // head
    const int pix = swz * 32 + pl;
    const int xr  = (pix >> 6) & 63;
    const int yc  = pix & 63;

    // q fragment (16 floats) in registers
    const float* qp = q + (size_t)pix * F + h * 16;
    float qv[16];
    *(float4*)(&qv[0])  = ((const float4*)qp)[0];
    *(float4*)(&qv[4])  = ((const float4*)qp)[1];
    *(float4*)(&qv[8])  = ((const float4*)qp)[2];
    *(float4*)(&qv[12]) = ((const float4*)qp)[3];

    // qe[a] = sum_d q[d]*emb[f][a]; emb0 term depends only on i, emb1 only on j
    const float* E = (h < 4) ? (emb0 + h * 16 * 7) : (emb1 + (h - 4) * 16 * 7);
    float qe[7] = {0.f, 0.f, 0.f, 0.f, 0.f, 0.f, 0.f};
#pragma unroll
    for (int d = 0; d < 16; ++d) {
#pragma unroll
        for (int a = 0; a < 7; ++a)
            qe[a] = fmaf(qv[d], E[d * 7 + a], qe[a]);
    }

    float m = -1e30f, l = 0.f;
    float o[16];
#pragma unroll
    for (int d = 0; d < 16; ++d) o[d] = 0.f;

#pragma unroll
    for (int i = 0; i < 7; ++i) {
        const int  xi    = xr + i - 3;
        const bool rowin = ((unsigned)xi < 64u);
        const int  npb   = pix + (i - 3) * 64 - 3;

        // --- batch-load all 7 key rows (28 dwordx4 in flight) ---
        float kb[7][16];
#pragma unroll
        for (int j = 0; j < 7; ++j) {
            int np = min(max(npb + j, 0), NPIX - 1);   // clamp; OOB discarded
            const float4* kp = (const float4*)(k + (size_t)np * F + h * 16);
            *(float4*)(&kb[j][0])  = kp[0];
            *(float4*)(&kb[j][4])  = kp[1];
            *(float4*)(&kb[j][8])  = kp[2];
            *(float4*)(&kb[j][12]) = kp[3];
        }

        // --- 7 independent scores ---
        float s[7];
#pragma unroll
        for (int j = 0; j < 7; ++j) {
            const int  yj  = yc + j - 3;
            const bool inb = rowin && ((unsigned)yj < 64u);
            float d0 = 0.f, d1 = 0.f, d2 = 0.f, d3 = 0.f;
#pragma unroll
            for (int d = 0; d < 4; ++d) {
                d0 = fmaf(qv[d],      kb[j][d],      d0);
                d1 = fmaf(qv[4 + d],  kb[j][4 + d],  d1);
                d2 = fmaf(qv[8 + d],  kb[j][8 + d],  d2);
                d3 = fmaf(qv[12 + d], kb[j][12 + d], d3);
            }
            const float dot = (d0 + d1) + (d2 + d3);
            s[j] = (inb ? dot : 0.f) + ((h < 4) ? qe[i] : qe[j]);
        }

        // --- batch-load all 7 value rows (issue before softmax to overlap) ---
        float vb[7][16];
#pragma unroll
        for (int j = 0; j < 7; ++j) {
            int np = min(max(npb + j, 0), NPIX - 1);
            const float4* vp = (const float4*)(v + (size_t)np * F + h * 16);
            *(float4*)(&vb[j][0])  = vp[0];
            *(float4*)(&vb[j][4])  = vp[1];
            *(float4*)(&vb[j][8])  = vp[2];
            *(float4*)(&vb[j][12]) = vp[3];
        }

        // --- online softmax row update (independent exps -> ILP) ---
        const float rm = fmaxf(fmaxf(fmaxf(s[0], s[1]), fmaxf(s[2], s[3])),
                               fmaxf(fmaxf(s[4], s[5]), s[6]));
        const float mn  = fmaxf(m, rm);
        const float cor = __expf(m - mn);
        float p[7];
#pragma unroll
        for (int j = 0; j < 7; ++j) p[j] = __expf(s[j] - mn);
        l = l * cor + (((p[0] + p[1]) + (p[2] + p[3])) + ((p[4] + p[5]) + p[6]));
        m = mn;
#pragma unroll
        for (int d = 0; d < 16; ++d) o[d] *= cor;

        // --- PV accumulate ---
#pragma unroll
        for (int j = 0; j < 7; ++j) {
            const int  yj  = yc + j - 3;
            const bool inb = rowin && ((unsigned)yj < 64u);
            const float pj = inb ? p[j] : 0.f;         // OOB v contributes 0
#pragma unroll
            for (int d = 0; d < 16; ++d) o[d] = fmaf(pj, vb[j][d], o[d]);
        }
    }

    const float inv = 1.f / l;
    float* op = out + (size_t)pix * F + h * 16;
    float ov[16];
#pragma unroll
    for (int d = 0; d < 16; ++d) ov[d] = o[d] * inv;
    ((float4*)op)[0] = *(float4*)(&ov[0]);
    ((float4*)op)[1] = *(float4*)(&ov[4]);
    ((float4*)op)[2] = *(float4*)(&ov[8]);
    ((float4*)op)[3] = *(float4*)(&ov[12]);
}

// --------------------------------------------------------------- launch -----
extern "C" void kernel_launch(void* const* d_in, const int* in_sizes, int n_in,
                              void* d_out, int out_size, void* d_ws, size_t ws_size,
                              hipStream_t stream)
{
    const float* x    = (const float*)d_in[0];
    const float* Wq   = (const float*)d_in[1];
    const float* bq   = (const float*)d_in[2];
    const float* Wk   = (const float*)d_in[3];
    const float* bk   = (const float*)d_in[4];
    const float* Wv   = (const float*)d_in[5];
    const float* bv   = (const float*)d_in[6];
    const float* emb0 = (const float*)d_in[7];
    const float* emb1 = (const float*)d_in[8];
    float* out = (float*)d_out;

    float* qb = (float*)d_ws;
    float* kb = qb + (size_t)NPIX * F;
    float* vb = kb + (size_t)NPIX * F;

    proj_kernel<<<(NPIX / 64) * 3, 256, 0, stream>>>(x, Wq, bq, Wk, bk, Wv, bv, qb, kb, vb);
    attn_kernel<<<NPIX / 32, 256, 0, stream>>>(qb, kb, vb, emb0, emb1, out);
}

// Round 19
// 147.079 us; speedup vs baseline: 2.4688x; 1.0840x over previous
//
#include <hip/hip_runtime.h>
#include <hip/hip_bf16.h>

// StandAloneSelfAttention: B=4, H=W=64, C=128, heads=8, hsize=16, K=7x7=49.
//   1) proj: q/k/v = x @ W + b. q stored f32; K/V stored bf16 (RNE) -> halves
//      attn's cache traffic. 768 blocks, XCD-swizzled.
//   2) attn: thread = (pixel, head); batched bf16 K/V loads (2x uint4 per row,
//      196 loads/thread vs 392 f32), f32 math after exact bf16->f32 unpack.
// Measured r11: attn latency/cache-BW bound (VALUBusy 16%, HBM 5%); harness
// poison memset ~55us is fixed overhead inside dur_us.

constexpr int C  = 128;
constexpr int F  = 128;
constexpr int NPIX = 4 * 64 * 64;   // 16384

__device__ __forceinline__ unsigned pack_bf16(float a, float b) {
    unsigned ua = __float_as_uint(a), ub = __float_as_uint(b);
    ua = (ua + 0x7FFFu + ((ua >> 16) & 1u)) >> 16;   // RNE bf16
    ub = (ub + 0x7FFFu + ((ub >> 16) & 1u)) >> 16;
    return ua | (ub << 16);
}

// ---------------------------------------------------------------- proj ------
template <bool BF16OUT>
__device__ __forceinline__ void do_proj(const float* __restrict__ W,
                                        const float* __restrict__ bias,
                                        void* __restrict__ outp,
                                        const float* __restrict__ xs,
                                        int p0, int tp, int tc)
{
    float acc[4][8];
#pragma unroll
    for (int i = 0; i < 4; ++i)
#pragma unroll
        for (int j = 0; j < 8; ++j) acc[i][j] = 0.f;

#pragma unroll 8
    for (int c = 0; c < 128; ++c) {
        const float4 w0 = *(const float4*)(W + c * 128 + tc * 8);
        const float4 w1 = *(const float4*)(W + c * 128 + tc * 8 + 4);
        const float wv[8] = {w0.x, w0.y, w0.z, w0.w, w1.x, w1.y, w1.z, w1.w};
        float xv[4];
#pragma unroll
        for (int i = 0; i < 4; ++i) xv[i] = xs[c * 65 + tp * 4 + i];
#pragma unroll
        for (int i = 0; i < 4; ++i)
#pragma unroll
            for (int j = 0; j < 8; ++j) acc[i][j] = fmaf(xv[i], wv[j], acc[i][j]);
    }

    float bv[8];
#pragma unroll
    for (int j = 0; j < 8; ++j) bv[j] = bias[tc * 8 + j];

#pragma unroll
    for (int i = 0; i < 4; ++i) {
        float r[8];
#pragma unroll
        for (int j = 0; j < 8; ++j) r[j] = acc[i][j] + bv[j];
        const int p = p0 + tp * 4 + i;
        if (BF16OUT) {
            uint4 u;
            u.x = pack_bf16(r[0], r[1]);
            u.y = pack_bf16(r[2], r[3]);
            u.z = pack_bf16(r[4], r[5]);
            u.w = pack_bf16(r[6], r[7]);
            *(uint4*)((unsigned short*)outp + (size_t)p * F + tc * 8) = u;
        } else {
            float4 o0 = {r[0], r[1], r[2], r[3]};
            float4 o1 = {r[4], r[5], r[6], r[7]};
            float* dst = (float*)outp + (size_t)p * F + tc * 8;
            *(float4*)(dst)     = o0;
            *(float4*)(dst + 4) = o1;
        }
    }
}

__global__ __launch_bounds__(256, 3) void proj_kernel(
    const float* __restrict__ x,
    const float* __restrict__ Wq, const float* __restrict__ bq,
    const float* __restrict__ Wk, const float* __restrict__ bk,
    const float* __restrict__ Wv, const float* __restrict__ bv,
    float* __restrict__ qo, unsigned short* __restrict__ ko,
    unsigned short* __restrict__ vo)
{
    __shared__ float xs[128 * 65];   // xs[c][p], stride 65 (bank-conflict-free)
    const int t   = threadIdx.x;
    // XCD swizzle: 768 blocks, 96 per XCD (768 % 8 == 0 -> bijective).
    const int bid = blockIdx.x;
    const int swz = (bid & 7) * 96 + (bid >> 3);
    const int g    = swz % 3;            // which GEMM (q/k/v)
    const int tile = swz / 3;            // 32 consecutive tiles per XCD
    const int p0   = tile * 64;

    for (int idx = t; idx < 64 * 128; idx += 256) {
        const int p = idx >> 7;
        const int c = idx & 127;
        xs[c * 65 + p] = x[(size_t)p0 * C + idx];
    }
    __syncthreads();

    const int tp = t >> 4, tc = t & 15;
    if (g == 0)      do_proj<false>(Wq, bq, qo, xs, p0, tp, tc);
    else if (g == 1) do_proj<true >(Wk, bk, ko, xs, p0, tp, tc);
    else             do_proj<true >(Wv, bv, vo, xs, p0, tp, tc);
}

// ---------------------------------------------------------------- attn ------
// thread = (pixel, head): block = 32 pixels x 8 heads = 256 threads.
__global__ __launch_bounds__(256, 1) void attn_kernel(
    const float* __restrict__ q, const unsigned short* __restrict__ k,
    const unsigned short* __restrict__ v, const float* __restrict__ emb0,
    const float* __restrict__ emb1, float* __restrict__ out)
{
    // XCD swizzle: 512 blocks, 64 per XCD -> K/V slab fits the 4 MB L2.
    const int bid = blockIdx.x;
    const int swz = (bid & 7) * 64 + (bid >> 3);

    const int t   = threadIdx.x;
    const int pl  = t >> 3;               // 0..31
    const int h   = t & 7;                // head
    const int pix = swz * 32 + pl;
    const int xr  = (pix >> 6) & 63;
    const int yc  = pix & 63;

    // q fragment (16 floats) in registers
    const float* qp = q + (size_t)pix * F + h * 16;
    float qv[16];
    *(float4*)(&qv[0])  = ((const float4*)qp)[0];
    *(float4*)(&qv[4])  = ((const float4*)qp)[1];
    *(float4*)(&qv[8])  = ((const float4*)qp)[2];
    *(float4*)(&qv[12]) = ((const float4*)qp)[3];

    // qe[a] = sum_d q[d]*emb[f][a]; emb0 term depends only on i, emb1 only on j
    const float* E = (h < 4) ? (emb0 + h * 16 * 7) : (emb1 + (h - 4) * 16 * 7);
    float qe[7] = {0.f, 0.f, 0.f, 0.f, 0.f, 0.f, 0.f};
#pragma unroll
    for (int d = 0; d < 16; ++d) {
#pragma unroll
        for (int a = 0; a < 7; ++a)
            qe[a] = fmaf(qv[d], E[d * 7 + a], qe[a]);
    }

    float m = -1e30f, l = 0.f;
    float o[16];
#pragma unroll
    for (int d = 0; d < 16; ++d) o[d] = 0.f;

#pragma unroll
    for (int i = 0; i < 7; ++i) {
        const int  xi    = xr + i - 3;
        const bool rowin = ((unsigned)xi < 64u);
        const int  npb   = pix + (i - 3) * 64 - 3;

        // --- batch-load all 7 key rows (14 x uint4 = 8 bf16 each, in flight) ---
        uint4 kraw[7][2];
#pragma unroll
        for (int j = 0; j < 7; ++j) {
            int np = min(max(npb + j, 0), NPIX - 1);   // clamp; OOB discarded
            const uint4* kp = (const uint4*)(k + (size_t)np * F + h * 16);
            kraw[j][0] = kp[0];
            kraw[j][1] = kp[1];
        }

        // --- 7 independent scores (exact bf16->f32 unpack, f32 FMA) ---
        float s[7];
#pragma unroll
        for (int j = 0; j < 7; ++j) {
            const int  yj  = yc + j - 3;
            const bool inb = rowin && ((unsigned)yj < 64u);
            const unsigned kw[8] = {kraw[j][0].x, kraw[j][0].y, kraw[j][0].z, kraw[j][0].w,
                                    kraw[j][1].x, kraw[j][1].y, kraw[j][1].z, kraw[j][1].w};
            float d0 = 0.f, d1 = 0.f, d2 = 0.f, d3 = 0.f;
#pragma unroll
            for (int u = 0; u < 4; ++u) {
                const float lo0 = __uint_as_float(kw[u] << 16);
                const float hi0 = __uint_as_float(kw[u] & 0xFFFF0000u);
                const float lo1 = __uint_as_float(kw[u + 4] << 16);
                const float hi1 = __uint_as_float(kw[u + 4] & 0xFFFF0000u);
                d0 = fmaf(qv[2 * u],     lo0, d0);
                d1 = fmaf(qv[2 * u + 1], hi0, d1);
                d2 = fmaf(qv[8 + 2 * u],     lo1, d2);
                d3 = fmaf(qv[8 + 2 * u + 1], hi1, d3);
            }
            const float dot = (d0 + d1) + (d2 + d3);
            s[j] = (inb ? dot : 0.f) + ((h < 4) ? qe[i] : qe[j]);
        }

        // --- batch-load all 7 value rows (overlap with softmax below) ---
        uint4 vraw[7][2];
#pragma unroll
        for (int j = 0; j < 7; ++j) {
            int np = min(max(npb + j, 0), NPIX - 1);
            const uint4* vp = (const uint4*)(v + (size_t)np * F + h * 16);
            vraw[j][0] = vp[0];
            vraw[j][1] = vp[1];
        }

        // --- online softmax row update (independent exps -> ILP) ---
        const float rm = fmaxf(fmaxf(fmaxf(s[0], s[1]), fmaxf(s[2], s[3])),
                               fmaxf(fmaxf(s[4], s[5]), s[6]));
        const float mn  = fmaxf(m, rm);
        const float cor = __expf(m - mn);
        float p[7];
#pragma unroll
        for (int j = 0; j < 7; ++j) p[j] = __expf(s[j] - mn);
        l = l * cor + (((p[0] + p[1]) + (p[2] + p[3])) + ((p[4] + p[5]) + p[6]));
        m = mn;
#pragma unroll
        for (int d = 0; d < 16; ++d) o[d] *= cor;

        // --- PV accumulate ---
#pragma unroll
        for (int j = 0; j < 7; ++j) {
            const int  yj  = yc + j - 3;
            const bool inb = rowin && ((unsigned)yj < 64u);
            const float pj = inb ? p[j] : 0.f;         // OOB v contributes 0
            const unsigned vw[8] = {vraw[j][0].x, vraw[j][0].y, vraw[j][0].z, vraw[j][0].w,
                                    vraw[j][1].x, vraw[j][1].y, vraw[j][1].z, vraw[j][1].w};
#pragma unroll
            for (int u = 0; u < 8; ++u) {
                const float lo = __uint_as_float(vw[u] << 16);
                const float hi = __uint_as_float(vw[u] & 0xFFFF0000u);
                o[2 * u]     = fmaf(pj, lo, o[2 * u]);
                o[2 * u + 1] = fmaf(pj, hi, o[2 * u + 1]);
            }
        }
    }

    const float inv = 1.f / l;
    float* op = out + (size_t)pix * F + h * 16;
    float ov[16];
#pragma unroll
    for (int d = 0; d < 16; ++d) ov[d] = o[d] * inv;
    ((float4*)op)[0] = *(float4*)(&ov[0]);
    ((float4*)op)[1] = *(float4*)(&ov[4]);
    ((float4*)op)[2] = *(float4*)(&ov[8]);
    ((float4*)op)[3] = *(float4*)(&ov[12]);
}

// --------------------------------------------------------------- launch -----
extern "C" void kernel_launch(void* const* d_in, const int* in_sizes, int n_in,
                              void* d_out, int out_size, void* d_ws, size_t ws_size,
                              hipStream_t stream)
{
    const float* x    = (const float*)d_in[0];
    const float* Wq   = (const float*)d_in[1];
    const float* bq   = (const float*)d_in[2];
    const float* Wk   = (const float*)d_in[3];
    const float* bk   = (const float*)d_in[4];
    const float* Wv   = (const float*)d_in[5];
    const float* bv   = (const float*)d_in[6];
    const float* emb0 = (const float*)d_in[7];
    const float* emb1 = (const float*)d_in[8];
    float* out = (float*)d_out;

    float* qb = (float*)d_ws;                                   // f32  8.4 MB
    unsigned short* kb = (unsigned short*)(qb + (size_t)NPIX * F);  // bf16 4.2 MB
    unsigned short* vb = kb + (size_t)NPIX * F;                     // bf16 4.2 MB

    proj_kernel<<<(NPIX / 64) * 3, 256, 0, stream>>>(x, Wq, bq, Wk, bk, Wv, bv, qb, kb, vb);
    attn_kernel<<<NPIX / 32, 256, 0, stream>>>(qb, kb, vb, emb0, emb1, out);
}